// Round 8
// baseline (14076.398 us; speedup 1.0000x reference)
//
#include <hip/hip_runtime.h>
#include <hip/hip_bf16.h>

// Problem: T=512, B=64, N=256, H=64, D=128, P=64.
// Stage 1: x2n = input(32768x128) @ W2n^T(128x256) + b2n          (gemm_xwT)
// Stage 2: 16384 independent LSTM cells scanned over 512 steps    (lstm_scan)
// Stage 3: out = ON(32768x256) @ Wout^T(256x64) + bout            (gemm_xwT)
// Workspace: x2n 32MB + ON 32MB = 64MB of d_ws.
//
// Scan (round-8): TLP, not ILP.  The per-step chain MFMA->NL->MFMA cannot
// overlap within a wave, and barrier-synced splits convoy (R3/R4 measured).
// Fix: 1024-thread blocks = 16 FREE-RUNNING waves (16 independent 16-cell
// groups, no barriers after init) -> 4 waves/SIMD co-resident, so one wave's
// NL (trans-pipe) overlaps another's MFMA (matrix pipe) — the m114 mechanism.
// Enabled by moving weights to block-shared LDS (34KB, one copy per 16
// waves): AFW fragment reads are conflict-free (16-lane phase = 256B
// contiguous = each bank once); w/b reads are same-address broadcasts.
// Ext-slice MFMA replaced by exact f32 fma(x,w,b) acc-init (-16 MFMA/step,
// better precision, no divergent fragment build).  Keeps round-7 NL
// (prescaled exp2 args, merged rcp), packed cvt, deferred g-reduction.

typedef __attribute__((ext_vector_type(4))) float f32x4;
typedef __attribute__((ext_vector_type(4))) short s16x4;
typedef __attribute__((ext_vector_type(8))) short s16x8;
typedef __attribute__((ext_vector_type(4))) unsigned u32x4;

__device__ inline short bf16r(float f) {            // round-to-nearest-even bf16
    unsigned u = __builtin_bit_cast(unsigned, f);
    u += 0x7fffu + ((u >> 16) & 1u);
    return (short)(u >> 16);
}
__device__ inline unsigned pkbf(float a, float b) { // (bf16(a) | bf16(b)<<16), RNE
    unsigned r;
    asm("v_cvt_pk_bf16_f32 %0, %1, %2" : "=v"(r) : "v"(a), "v"(b));
    return r;
}
__device__ inline f32x4 mfma32(s16x8 a, s16x8 b, f32x4 c) {
    return __builtin_amdgcn_mfma_f32_16x16x32_bf16(a, b, c, 0, 0, 0);
}

// ---------------------------------------------------------------------------
// Generic fp32 GEMM: Out(MxN) = X(MxK) @ Wt(NxK)^T + bias(N).  M%64==0,
// N%64==0, K%32==0.  grid = (M/64, N/64), block = 256.
// ---------------------------------------------------------------------------
__global__ __launch_bounds__(256) void gemm_xwT(
    const float* __restrict__ X, const float* __restrict__ Wt,
    const float* __restrict__ bias, float* __restrict__ Out,
    int N, int K)
{
    __shared__ float Xs[32][68];
    __shared__ float Ws[32][68];
    const int tid = threadIdx.x;
    const int tx = tid & 15, ty = tid >> 4;
    const int m0 = blockIdx.x * 64, n0 = blockIdx.y * 64;
    const int kq = tid & 7, mr = tid >> 3;

    float acc[4][4];
#pragma unroll
    for (int i = 0; i < 4; ++i)
#pragma unroll
        for (int j = 0; j < 4; ++j) acc[i][j] = 0.f;

    for (int kc = 0; kc < K; kc += 32) {
#pragma unroll
        for (int rr = 0; rr < 2; ++rr) {
            const int m = mr + rr * 32;
            f32x4 xv = *(const f32x4*)(X + (size_t)(m0 + m) * K + kc + kq * 4);
            f32x4 wv = *(const f32x4*)(Wt + (size_t)(n0 + m) * K + kc + kq * 4);
#pragma unroll
            for (int j = 0; j < 4; ++j) { Xs[kq*4 + j][m] = xv[j]; Ws[kq*4 + j][m] = wv[j]; }
        }
        __syncthreads();
#pragma unroll
        for (int k = 0; k < 32; ++k) {
            f32x4 a = *(const f32x4*)&Xs[k][ty * 4];
            f32x4 b = *(const f32x4*)&Ws[k][tx * 4];
#pragma unroll
            for (int i = 0; i < 4; ++i)
#pragma unroll
                for (int j = 0; j < 4; ++j)
                    acc[i][j] = __builtin_fmaf(a[i], b[j], acc[i][j]);
        }
        __syncthreads();
    }
    f32x4 bv = *(const f32x4*)(bias + n0 + tx * 4);
#pragma unroll
    for (int i = 0; i < 4; ++i) {
        f32x4 o;
#pragma unroll
        for (int j = 0; j < 4; ++j) o[j] = acc[i][j] + bv[j];
        *(f32x4*)(Out + (size_t)(m0 + ty * 4 + i) * N + n0 + tx * 4) = o;
    }
}

// ---------------------------------------------------------------------------
// Recurrent scan.  64 blocks x 1024 threads; wave w of block b owns the 16
// cells of group b*16+w for all 512 steps, free-running (no barriers after
// weight staging).  4 waves/SIMD co-resident on 64 CUs.
//
// MFMA 16x16x32 bf16 layouts, lane l, c15=l&15, g4=l>>4:
//   A: lane elems 0-3 hold A[c15][kbase + 4*g4 + e], elems 4-7: +16
//   B: lane elems 0-3 hold B[kbase + 4*g4 + e][c15], elems 4-7: +16
//   D: lane reg e holds D[4*g4 + e][c15]
//
// acc[nt] (nt=0..15): lane (g4,c15) elem e = PRE-SCALED gate nt*16+4g4+e of
// cell c15; type=nt>>2 in {i,f,g,o}; scale -log2e for i/f/o, +2log2e for g.
// acc init = sc*(x*w_ih + bias) computed in exact f32 from LDS-held w/b.
// ---------------------------------------------------------------------------
__global__ __launch_bounds__(1024) void lstm_scan(
    const float* __restrict__ x2n,   // [512][16384]
    const float* __restrict__ W_hh,  // [256][64]
    const float* __restrict__ w_ih,  // [256]
    const float* __restrict__ b_ih,  // [256]
    const float* __restrict__ b_hh,  // [256]
    const float* __restrict__ wg,    // [64]
    const float* __restrict__ bg,    // [1]
    float* __restrict__ ON)          // [512][16384]
{
    __shared__ s16x8 AFW[16][2][64];   // per-lane W_hh A-fragments, 32KB
    __shared__ f32x4 WB[2][16][4];     // [w|b][nt][g4] prescaled f32, 2KB

    const int tid = threadIdx.x;
    const int lane = tid & 63;
    const int wv = tid >> 6;
    const int c15 = lane & 15, g4 = lane >> 4;
    const int cellbase = (blockIdx.x * 16 + wv) * 16;
    const float L2E = 1.4426950408889634f;

    // ---- cooperative weight staging (once) ----
#pragma unroll
    for (int idx = tid; idx < 2048; idx += 1024) {
        const int nt = idx >> 7, kp = (idx >> 6) & 1, l = idx & 63;
        const int cc = l & 15, gg = l >> 4;
        const float sc = ((nt >> 2) == 2) ? (2.f * L2E) : (-L2E);
        const float* wrow = W_hh + (size_t)(nt * 16 + cc) * 64;
        s16x8 v;
#pragma unroll
        for (int half = 0; half < 2; ++half) {
            f32x4 w = *(const f32x4*)(wrow + kp * 32 + half * 16 + gg * 4);
#pragma unroll
            for (int e = 0; e < 4; ++e) v[half * 4 + e] = bf16r(w[e] * sc);
        }
        AFW[nt][kp][l] = v;
    }
    if (tid < 128) {
        const int which = tid >> 6, r = tid & 63;
        const int nt = r >> 2, gg = r & 3;
        const float sc = ((nt >> 2) == 2) ? (2.f * L2E) : (-L2E);
        f32x4 v;
#pragma unroll
        for (int e = 0; e < 4; ++e) {
            const int g = nt * 16 + gg * 4 + e;
            v[e] = (which == 0) ? (w_ih[g] * sc) : ((b_ih[g] + b_hh[g]) * sc);
        }
        WB[which][nt][gg] = v;
    }
    __syncthreads();   // the only barrier; LDS read-only afterwards

    // wg, laid out to match hvf: wg_l[q][e] = wg[q*16 + 4*g4 + e]
    f32x4 wg_l[4];
#pragma unroll
    for (int q = 0; q < 4; ++q) wg_l[q] = *(const f32x4*)(wg + q * 16 + g4 * 4);
    const float bg0 = bg[0];

    f32x4 cst[4];
#pragma unroll
    for (int q = 0; q < 4; ++q) cst[q] = (f32x4){0.f, 0.f, 0.f, 0.f};
    s16x8 bh01 = (s16x8){0, 0, 0, 0, 0, 0, 0, 0};   // h k=0..31  B-fragment
    s16x8 bh23 = (s16x8){0, 0, 0, 0, 0, 0, 0, 0};   // h k=32..63 B-fragment

    float g_s1 = 0.f;      // xor16-reduced g-partial of step t-1
    float g2save = 0.f;    // fully-reduced g of step t-2
    float sp0 = 0.f;

    const size_t cellidx = (size_t)cellbase + c15;
    float xs = x2n[cellidx];          // x for (t=0, cell c15), prefetched

    for (int t = 0; t < 512; ++t) {
        // finish step t-1's g-reduction (independent of everything below)
        const float s2new = g_s1 + __shfl_xor(g_s1, 32, 64);

        const float xs_cur = xs;
        xs = x2n[(size_t)((t + 1) & 511) * 16384 + cellidx];   // branchless

        // gates^T (pre-scaled): f32 (x*w+b) init + two K=32 slices of W_hh@h^T
        f32x4 acc[16];
#pragma unroll
        for (int nt = 0; nt < 16; ++nt) {
            const f32x4 wvv = WB[0][nt][g4];    // broadcast reads
            const f32x4 bvv = WB[1][nt][g4];
            f32x4 c0;
#pragma unroll
            for (int e = 0; e < 4; ++e) c0[e] = __builtin_fmaf(xs_cur, wvv[e], bvv[e]);
            c0 = mfma32(AFW[nt][0][lane], bh01, c0);
            acc[nt] = mfma32(AFW[nt][1][lane], bh23, c0);
        }

        // ---- merged nonlinearities (rcp-paired across qa/qb) ----
        f32x4 hvf[4];
#pragma unroll
        for (int qp = 0; qp < 2; ++qp) {
            const int qa = 2 * qp, qb = qa + 1;
            f32x4 cna, cnb, hna, hnb;
#pragma unroll
            for (int e = 0; e < 4; ++e) {
                const float ufa = __builtin_amdgcn_exp2f(acc[qa + 4][e]);
                const float ufb = __builtin_amdgcn_exp2f(acc[qb + 4][e]);
                const float dfa = 1.f + ufa, dfb = 1.f + ufb;
                const float rf = __builtin_amdgcn_rcpf(dfa * dfb);
                const float sfa = rf * dfb, sfb = rf * dfa;

                const float uia = __builtin_amdgcn_exp2f(acc[qa][e]);
                const float uib = __builtin_amdgcn_exp2f(acc[qb][e]);
                const float vga = __builtin_amdgcn_exp2f(acc[qa + 8][e]);
                const float vgb = __builtin_amdgcn_exp2f(acc[qb + 8][e]);
                const float pa = (vga - 1.f) *
                    __builtin_amdgcn_rcpf((1.f + uia) * (1.f + vga));
                const float pb = (vgb - 1.f) *
                    __builtin_amdgcn_rcpf((1.f + uib) * (1.f + vgb));

                const float ca = __builtin_fmaf(sfa, cst[qa][e], pa);
                const float cb = __builtin_fmaf(sfb, cst[qb][e], pb);
                cna[e] = ca; cnb[e] = cb;

                const float uoa = __builtin_amdgcn_exp2f(acc[qa + 12][e]);
                const float uob = __builtin_amdgcn_exp2f(acc[qb + 12][e]);
                const float vca = __builtin_amdgcn_exp2f(fminf(2.8853900817779268f * ca, 43.f));
                const float vcb = __builtin_amdgcn_exp2f(fminf(2.8853900817779268f * cb, 43.f));
                hna[e] = (vca - 1.f) * __builtin_amdgcn_rcpf((1.f + uoa) * (1.f + vca));
                hnb[e] = (vcb - 1.f) * __builtin_amdgcn_rcpf((1.f + uob) * (1.f + vcb));
            }
            cst[qa] = cna; cst[qb] = cnb;
            hvf[qa] = hna; hvf[qb] = hnb;
        }

        // next-step B fragments via packed cvt (RNE), directly as K=32 pairs
        bh01 = __builtin_bit_cast(s16x8,
                   (u32x4){pkbf(hvf[0][0], hvf[0][1]), pkbf(hvf[0][2], hvf[0][3]),
                           pkbf(hvf[1][0], hvf[1][1]), pkbf(hvf[1][2], hvf[1][3])});
        bh23 = __builtin_bit_cast(s16x8,
                   (u32x4){pkbf(hvf[2][0], hvf[2][1]), pkbf(hvf[2][2], hvf[2][3]),
                           pkbf(hvf[3][0], hvf[3][1]), pkbf(hvf[3][2], hvf[3][3])});

        // g_t raw partial, two independent chains (first shuffle at iter end)
        float gA = 0.f, gB = 0.f;
#pragma unroll
        for (int e = 0; e < 4; ++e) {
            gA = __builtin_fmaf(hvf[0][e], wg_l[0][e], gA);
            gA = __builtin_fmaf(hvf[1][e], wg_l[1][e], gA);
            gB = __builtin_fmaf(hvf[2][e], wg_l[2][e], gB);
            gB = __builtin_fmaf(hvf[3][e], wg_l[3][e], gB);
        }
        const float gpart = gA + gB;

        // out[t,cell] = gain * softplus(x-1); gain = g_t, 1, g_{t-2}
        const float x1 = xs_cur - 1.f;
        const float sp = fmaxf(x1, 0.f) +
            0.6931471805599453f * __builtin_amdgcn_logf(
                1.f + __builtin_amdgcn_exp2f(-1.4426950408889634f * fabsf(x1)));
        if (t >= 2) {
            const float gain = g2save + bg0;         // = g_{t-2}
            if (g4 == 0) {
                ON[(size_t)t * 16384 + cellidx] = gain * sp;
                if (t == 2) ON[cellidx] = gain * sp0;          // gain_0 = g_0
            }
        } else if (t == 1) {
            if (g4 == 0) ON[(size_t)16384 + cellidx] = sp;     // gain = 1
        } else {
            sp0 = sp;                                // ON[0] deferred to t==2
        }
        g2save = s2new;                              // s2 of step t-1
        g_s1 = gpart + __shfl_xor(gpart, 16, 64);    // s1 of step t
    }
}

extern "C" void kernel_launch(void* const* d_in, const int* in_sizes, int n_in,
                              void* d_out, int out_size, void* d_ws, size_t ws_size,
                              hipStream_t stream)
{
    const float* input = (const float*)d_in[0];   // [512][64][128]
    const float* W2n   = (const float*)d_in[1];   // [256][128]
    const float* b2n   = (const float*)d_in[2];   // [256]
    const float* W_ih  = (const float*)d_in[3];   // [256] (4H x 1)
    const float* W_hh  = (const float*)d_in[4];   // [256][64]
    const float* b_ih  = (const float*)d_in[5];   // [256]
    const float* b_hh  = (const float*)d_in[6];   // [256]
    const float* Wg    = (const float*)d_in[7];   // [64]  (1 x H)
    const float* bg    = (const float*)d_in[8];   // [1]
    const float* Wout  = (const float*)d_in[9];   // [64][256]
    const float* bout  = (const float*)d_in[10];  // [64]

    float* x2n = (float*)d_ws;                          // 512*16384 f32 = 32MB
    float* ON  = x2n + (size_t)512 * 16384;             // another 32MB

    // Stage 1: x2n = input @ W2n^T + b2n   (M=32768, N=256, K=128)
    gemm_xwT<<<dim3(512, 4), 256, 0, stream>>>(input, W2n, b2n, x2n, 256, 128);

    // Stage 2: recurrent scan -> ON  (64 blocks x 1024 thr = 4 waves/SIMD)
    lstm_scan<<<64, 1024, 0, stream>>>(x2n, W_hh, W_ih, b_ih, b_hh, Wg, bg, ON);

    // Stage 3: out = ON @ Wout^T + bout    (M=32768, N=64, K=256)
    gemm_xwT<<<dim3(512, 1), 256, 0, stream>>>(ON, Wout, bout, (float*)d_out, 64, 256);
}

// Round 9
// 873.355 us; speedup vs baseline: 16.1176x; 16.1176x over previous
//
#include <hip/hip_runtime.h>
#include <hip/hip_bf16.h>

// Problem: T=512, B=64, N=256, H=64, D=128, P=64.
// Stage 1: x2n = input(32768x128) @ W2n^T(128x256) + b2n          (gemm_xwT)
// Stage 2: 16384 independent LSTM cells scanned over 512 steps    (lstm_scan)
// Stage 3: out = ON(32768x256) @ Wout^T(256x64) + bout            (gemm_xwT)
// Workspace: x2n 32MB + ON 32MB = 64MB of d_ws.
//
// Scan (round-9): 1 wave/SIMD on all 1024 SIMDs (R8 proved concentration
// loses: only 1024 waves exist, and trans = 16 cyc/wave-instr means the
// trans floor is 512 steps x 1952 cyc ~ 417us with EVERYTHING else hidden).
// The win is intra-wave overlap: GATE-TYPE-MAJOR restructure — per q=0..3
// compute the 4 gate tiles (i,f,g,o; 8 MFMAs) then immediately that q's
// nonlinearity, giving 4 independent MFMA->NL chains so q+1's MFMAs issue
// while q's trans work drains (R7 had all-MFMA-then-all-NL: trans util 48%,
// trans pipe idle during the 840-cyc MFMA block).
// Ext-slice MFMA dropped: exact f32 fma(x,w,b) acc-init from a 2KB LDS
// table (R8-verified numerics), -16 MFMAs/step, no divergent bx8 build.
// Keeps: K=32 MFMA, register-resident pre-scaled W_hh fragments (pinned),
// merged-rcp NL, packed cvt h->bf16, deferred 2-step g-reduction.

typedef __attribute__((ext_vector_type(4))) float f32x4;
typedef __attribute__((ext_vector_type(4))) short s16x4;
typedef __attribute__((ext_vector_type(8))) short s16x8;
typedef __attribute__((ext_vector_type(4))) unsigned u32x4;

__device__ inline short bf16r(float f) {            // round-to-nearest-even bf16
    unsigned u = __builtin_bit_cast(unsigned, f);
    u += 0x7fffu + ((u >> 16) & 1u);
    return (short)(u >> 16);
}
__device__ inline unsigned pkbf(float a, float b) { // (bf16(a) | bf16(b)<<16), RNE
    unsigned r;
    asm("v_cvt_pk_bf16_f32 %0, %1, %2" : "=v"(r) : "v"(a), "v"(b));
    return r;
}
__device__ inline f32x4 mfma32(s16x8 a, s16x8 b, f32x4 c) {
    return __builtin_amdgcn_mfma_f32_16x16x32_bf16(a, b, c, 0, 0, 0);
}

// ---------------------------------------------------------------------------
// Generic fp32 GEMM: Out(MxN) = X(MxK) @ Wt(NxK)^T + bias(N).  M%64==0,
// N%64==0, K%32==0.  grid = (M/64, N/64), block = 256.
// ---------------------------------------------------------------------------
__global__ __launch_bounds__(256) void gemm_xwT(
    const float* __restrict__ X, const float* __restrict__ Wt,
    const float* __restrict__ bias, float* __restrict__ Out,
    int N, int K)
{
    __shared__ float Xs[32][68];
    __shared__ float Ws[32][68];
    const int tid = threadIdx.x;
    const int tx = tid & 15, ty = tid >> 4;
    const int m0 = blockIdx.x * 64, n0 = blockIdx.y * 64;
    const int kq = tid & 7, mr = tid >> 3;

    float acc[4][4];
#pragma unroll
    for (int i = 0; i < 4; ++i)
#pragma unroll
        for (int j = 0; j < 4; ++j) acc[i][j] = 0.f;

    for (int kc = 0; kc < K; kc += 32) {
#pragma unroll
        for (int rr = 0; rr < 2; ++rr) {
            const int m = mr + rr * 32;
            f32x4 xv = *(const f32x4*)(X + (size_t)(m0 + m) * K + kc + kq * 4);
            f32x4 wv = *(const f32x4*)(Wt + (size_t)(n0 + m) * K + kc + kq * 4);
#pragma unroll
            for (int j = 0; j < 4; ++j) { Xs[kq*4 + j][m] = xv[j]; Ws[kq*4 + j][m] = wv[j]; }
        }
        __syncthreads();
#pragma unroll
        for (int k = 0; k < 32; ++k) {
            f32x4 a = *(const f32x4*)&Xs[k][ty * 4];
            f32x4 b = *(const f32x4*)&Ws[k][tx * 4];
#pragma unroll
            for (int i = 0; i < 4; ++i)
#pragma unroll
                for (int j = 0; j < 4; ++j)
                    acc[i][j] = __builtin_fmaf(a[i], b[j], acc[i][j]);
        }
        __syncthreads();
    }
    f32x4 bv = *(const f32x4*)(bias + n0 + tx * 4);
#pragma unroll
    for (int i = 0; i < 4; ++i) {
        f32x4 o;
#pragma unroll
        for (int j = 0; j < 4; ++j) o[j] = acc[i][j] + bv[j];
        *(f32x4*)(Out + (size_t)(m0 + ty * 4 + i) * N + n0 + tx * 4) = o;
    }
}

// ---------------------------------------------------------------------------
// Recurrent scan, register-only h.  1024 blocks x 64 threads; each wave owns
// 16 cells (cell = cellbase + (lane&15)) for all 512 steps.
//
// MFMA 16x16x32 bf16 layouts, lane l, c15=l&15, g4=l>>4:
//   A: lane elems 0-3 hold A[c15][kbase + 4*g4 + e], elems 4-7: +16
//   B: lane elems 0-3 hold B[kbase + 4*g4 + e][c15], elems 4-7: +16
//   D: lane reg e holds D[4*g4 + e][c15]
//
// Tile nt = type*4 + q (type 0..3 = i,f,g,o; q = j-block).  Lane (g4,c15)
// elem e of tile nt = PRE-SCALED gate nt*16+4g4+e of cell c15; scale -log2e
// for i/f/o rows, +2log2e for g rows.  acc init = sc*(x*w_ih + bias) in f32.
// ---------------------------------------------------------------------------
__global__ __launch_bounds__(64, 1) void lstm_scan(
    const float* __restrict__ x2n,   // [512][16384]
    const float* __restrict__ W_hh,  // [256][64]
    const float* __restrict__ w_ih,  // [256]
    const float* __restrict__ b_ih,  // [256]
    const float* __restrict__ b_hh,  // [256]
    const float* __restrict__ wg,    // [64]
    const float* __restrict__ bg,    // [1]
    float* __restrict__ ON)          // [512][16384]
{
    __shared__ f32x4 WB[2][16][4];   // [w|b][nt][g4] prescaled f32, 2KB

    const int lane = threadIdx.x & 63;
    const int c15 = lane & 15, g4 = lane >> 4;
    const int cellbase = blockIdx.x * 16;
    const float L2E = 1.4426950408889634f;

    // stage WB (single wave = whole block; no barrier needed, just lgkmcnt
    // which the compiler inserts before first read)
#pragma unroll
    for (int it = 0; it < 2; ++it) {
        const int idx = it * 64 + lane;          // 0..127
        const int which = idx >> 6, r = idx & 63;
        const int nt = r >> 2, gg = r & 3;
        const float sc = ((nt >> 2) == 2) ? (2.f * L2E) : (-L2E);
        f32x4 v;
#pragma unroll
        for (int e = 0; e < 4; ++e) {
            const int g = nt * 16 + gg * 4 + e;
            v[e] = (which == 0) ? (w_ih[g] * sc) : ((b_ih[g] + b_hh[g]) * sc);
        }
        WB[which][nt][gg] = v;
    }

    // W_hh A-fragments (K=32 pairs), PRE-SCALED, register-resident.
    s16x8 afw8[2][16];
#pragma unroll
    for (int nt = 0; nt < 16; ++nt) {
        const float sc = ((nt >> 2) == 2) ? (2.f * L2E) : (-L2E);
        const float* wrow = W_hh + (size_t)(nt * 16 + c15) * 64;
#pragma unroll
        for (int kp = 0; kp < 2; ++kp) {
            s16x8 v;
#pragma unroll
            for (int half = 0; half < 2; ++half) {
                f32x4 w = *(const f32x4*)(wrow + (kp * 2 + half) * 16 + g4 * 4);
#pragma unroll
                for (int e = 0; e < 4; ++e) v[half * 4 + e] = bf16r(w[e] * sc);
            }
            afw8[kp][nt] = v;
        }
    }
    // Pin: breaks rematerialization-from-memory (R6: compiler re-loaded
    // weights from global every step when unpinned).
#pragma unroll
    for (int nt = 0; nt < 16; ++nt) {
        asm volatile("" : "+v"(afw8[0][nt]));
        asm volatile("" : "+v"(afw8[1][nt]));
    }

    // wg, laid out to match hvf: wg_l[q][e] = wg[q*16 + 4*g4 + e]
    f32x4 wg_l[4];
#pragma unroll
    for (int q = 0; q < 4; ++q) wg_l[q] = *(const f32x4*)(wg + q * 16 + g4 * 4);
    const float bg0 = bg[0];

    f32x4 cst[4];
#pragma unroll
    for (int q = 0; q < 4; ++q) cst[q] = (f32x4){0.f, 0.f, 0.f, 0.f};
    s16x8 bh01 = (s16x8){0, 0, 0, 0, 0, 0, 0, 0};   // h k=0..31  B-fragment
    s16x8 bh23 = (s16x8){0, 0, 0, 0, 0, 0, 0, 0};   // h k=32..63 B-fragment

    float g_s1 = 0.f;      // xor16-reduced g-partial of step t-1
    float g2save = 0.f;    // fully-reduced g of step t-2
    float sp0 = 0.f;

    const size_t cellidx = (size_t)cellbase + c15;
    float xs = x2n[cellidx];          // x for (t=0, cell c15), prefetched

    for (int t = 0; t < 512; ++t) {
        // finish step t-1's g-reduction (independent of everything below)
        const float s2new = g_s1 + __shfl_xor(g_s1, 32, 64);

        const float xs_cur = xs;
        xs = x2n[(size_t)((t + 1) & 511) * 16384 + cellidx];   // branchless

        // -------- gate-type-major: per q, 8 MFMAs then that q's NL --------
        unsigned bhw[8];        // next-step bh words (static-indexed, unrolled)
        float gpart = 0.f;
#pragma unroll
        for (int q = 0; q < 4; ++q) {
            // 4 gate tiles of this q: nt = type*4 + q
            f32x4 ai, af, ag, ao;
            {
                const f32x4 wi = WB[0][q][g4],      bi = WB[1][q][g4];
                const f32x4 wf = WB[0][q + 4][g4],  bf = WB[1][q + 4][g4];
                const f32x4 wgg = WB[0][q + 8][g4], bgg = WB[1][q + 8][g4];
                const f32x4 wo = WB[0][q + 12][g4], bo = WB[1][q + 12][g4];
#pragma unroll
                for (int e = 0; e < 4; ++e) {
                    ai[e] = __builtin_fmaf(xs_cur, wi[e], bi[e]);
                    af[e] = __builtin_fmaf(xs_cur, wf[e], bf[e]);
                    ag[e] = __builtin_fmaf(xs_cur, wgg[e], bgg[e]);
                    ao[e] = __builtin_fmaf(xs_cur, wo[e], bo[e]);
                }
            }
            ai = mfma32(afw8[0][q], bh01, ai);      ai = mfma32(afw8[1][q], bh23, ai);
            af = mfma32(afw8[0][q + 4], bh01, af);  af = mfma32(afw8[1][q + 4], bh23, af);
            ag = mfma32(afw8[0][q + 8], bh01, ag);  ag = mfma32(afw8[1][q + 8], bh23, ag);
            ao = mfma32(afw8[0][q + 12], bh01, ao); ao = mfma32(afw8[1][q + 12], bh23, ao);

            // NL for this q's 4 elements (e-pairs share the f-rcp)
            f32x4 hv;
#pragma unroll
            for (int ep = 0; ep < 2; ++ep) {
                const int ea = 2 * ep, eb = ea + 1;
                const float ufa = __builtin_amdgcn_exp2f(af[ea]);
                const float ufb = __builtin_amdgcn_exp2f(af[eb]);
                const float dfa = 1.f + ufa, dfb = 1.f + ufb;
                const float rf = __builtin_amdgcn_rcpf(dfa * dfb);
                const float sfa = rf * dfb, sfb = rf * dfa;

                const float uia = __builtin_amdgcn_exp2f(ai[ea]);
                const float uib = __builtin_amdgcn_exp2f(ai[eb]);
                const float vga = __builtin_amdgcn_exp2f(ag[ea]);
                const float vgb = __builtin_amdgcn_exp2f(ag[eb]);
                const float pa = (vga - 1.f) *
                    __builtin_amdgcn_rcpf((1.f + uia) * (1.f + vga));
                const float pb = (vgb - 1.f) *
                    __builtin_amdgcn_rcpf((1.f + uib) * (1.f + vgb));

                const float ca = __builtin_fmaf(sfa, cst[q][ea], pa);
                const float cb = __builtin_fmaf(sfb, cst[q][eb], pb);
                cst[q][ea] = ca; cst[q][eb] = cb;

                const float uoa = __builtin_amdgcn_exp2f(ao[ea]);
                const float uob = __builtin_amdgcn_exp2f(ao[eb]);
                const float vca = __builtin_amdgcn_exp2f(fminf(2.8853900817779268f * ca, 43.f));
                const float vcb = __builtin_amdgcn_exp2f(fminf(2.8853900817779268f * cb, 43.f));
                const float ha = (vca - 1.f) * __builtin_amdgcn_rcpf((1.f + uoa) * (1.f + vca));
                const float hb = (vcb - 1.f) * __builtin_amdgcn_rcpf((1.f + uob) * (1.f + vcb));
                hv[ea] = ha; hv[eb] = hb;
                bhw[q * 2 + ep] = pkbf(ha, hb);     // B-fragment word
            }
            gpart = __builtin_fmaf(hv[0], wg_l[q][0], gpart);
            gpart = __builtin_fmaf(hv[1], wg_l[q][1], gpart);
            gpart = __builtin_fmaf(hv[2], wg_l[q][2], gpart);
            gpart = __builtin_fmaf(hv[3], wg_l[q][3], gpart);
        }

        // assemble next-step B fragments (all static indices)
        bh01 = __builtin_bit_cast(s16x8, (u32x4){bhw[0], bhw[1], bhw[2], bhw[3]});
        bh23 = __builtin_bit_cast(s16x8, (u32x4){bhw[4], bhw[5], bhw[6], bhw[7]});

        // out[t,cell] = gain * softplus(x-1); gain = g_t, 1, g_{t-2}
        const float x1 = xs_cur - 1.f;
        const float sp = fmaxf(x1, 0.f) +
            0.6931471805599453f * __builtin_amdgcn_logf(
                1.f + __builtin_amdgcn_exp2f(-1.4426950408889634f * fabsf(x1)));
        if (t >= 2) {
            const float gain = g2save + bg0;         // = g_{t-2}
            if (g4 == 0) {
                ON[(size_t)t * 16384 + cellidx] = gain * sp;
                if (t == 2) ON[cellidx] = gain * sp0;          // gain_0 = g_0
            }
        } else if (t == 1) {
            if (g4 == 0) ON[(size_t)16384 + cellidx] = sp;     // gain = 1
        } else {
            sp0 = sp;                                // ON[0] deferred to t==2
        }
        g2save = s2new;                              // s2 of step t-1
        g_s1 = gpart + __shfl_xor(gpart, 16, 64);    // s1 of step t
    }
}

extern "C" void kernel_launch(void* const* d_in, const int* in_sizes, int n_in,
                              void* d_out, int out_size, void* d_ws, size_t ws_size,
                              hipStream_t stream)
{
    const float* input = (const float*)d_in[0];   // [512][64][128]
    const float* W2n   = (const float*)d_in[1];   // [256][128]
    const float* b2n   = (const float*)d_in[2];   // [256]
    const float* W_ih  = (const float*)d_in[3];   // [256] (4H x 1)
    const float* W_hh  = (const float*)d_in[4];   // [256][64]
    const float* b_ih  = (const float*)d_in[5];   // [256]
    const float* b_hh  = (const float*)d_in[6];   // [256]
    const float* Wg    = (const float*)d_in[7];   // [64]  (1 x H)
    const float* bg    = (const float*)d_in[8];   // [1]
    const float* Wout  = (const float*)d_in[9];   // [64][256]
    const float* bout  = (const float*)d_in[10];  // [64]

    float* x2n = (float*)d_ws;                          // 512*16384 f32 = 32MB
    float* ON  = x2n + (size_t)512 * 16384;             // another 32MB

    // Stage 1: x2n = input @ W2n^T + b2n   (M=32768, N=256, K=128)
    gemm_xwT<<<dim3(512, 4), 256, 0, stream>>>(input, W2n, b2n, x2n, 256, 128);

    // Stage 2: recurrent scan -> ON  (1024 waves = 1/SIMD on all 256 CUs)
    lstm_scan<<<1024, 64, 0, stream>>>(x2n, W_hh, W_ih, b_ih, b_hh, Wg, bg, ON);

    // Stage 3: out = ON @ Wout^T + bout    (M=32768, N=64, K=256)
    gemm_xwT<<<dim3(512, 1), 256, 0, stream>>>(ON, Wout, bout, (float*)d_out, 64, 256);
}